// Round 15
// baseline (104.762 us; speedup 1.0000x reference)
//
#include <hip/hip_runtime.h>

#define BB 4096
#define TT 512
#define HH 10
#define L2E 1.44269504088896340736f

typedef __fp16 half2_t __attribute__((ext_vector_type(2)));

__device__ __forceinline__ float rcp_(float x) { return __builtin_amdgcn_rcpf(x); }
__device__ __forceinline__ float exp2_(float x) { return __builtin_amdgcn_exp2f(x); }

// DPP helpers. quad_perm ctrl 0x00-0xFF; row_ror:N = 0x120|N (dst[i] = src[(i+N)&15],
// within each 16-lane row). update_dpp(old, src, ctrl, row_mask, bank_mask, bound):
// lanes outside row/bank masks keep `old` — used to merge rotations into one register.
template <int CTRL, int BANK = 0xF>
__device__ __forceinline__ int dppi_(int old, int src) {
    return __builtin_amdgcn_update_dpp(old, src, CTRL, 0xF, BANK, true);
}
template <int CTRL>
__device__ __forceinline__ float dpp_(float v) {
    return __int_as_float(__builtin_amdgcn_update_dpp(
        0, __float_as_int(v), CTRL, 0xF, 0xF, true));
}
#define QP_XOR1 0xB1   // [1,0,3,2]
#define QP_XOR2 0x4E   // [2,3,0,1]
#define QP_B0   0x00   // broadcast quad lane 0
#define QP_B2   0xAA   // broadcast quad lane 2
#define ROR4    0x124
#define ROR8    0x128
#define ROR12   0x12C

// 16 lanes per batch element (4 elements/wave, 1024 waves = 1/SIMD chip-wide).
// Owner lane u<10 holds all 4 gate rows {u,10+u,20+u,30+u}, f16-packed for
// v_dot2_f32_f16, PRE-SCALED by -log2e / -2log2e so accumulators feed exp2 directly.
// SINGLE-RCP cell update: with A=e^-i, F=e^-f, G=e^-2g,
//   cn = [c(1+A)(1+G) + (1+F)(1-G)] / [(1+F)(1+A)(1+G)]   (one rcp)
//   h  = (1-T)/((1+O)(1+T)), T = 2^(-2 log2e * cn)         (one rcp)
// Gate/regressor dot2s use 2-accumulator trees (chain 5->3). Regressor is
// software-pipelined one step behind (fills the act-chain stall). Reduce tail uses
// 3 parallel rotations + add tree. Broadcast is the validated trimmed DPP tree.
__global__ __launch_bounds__(64) void lstm16r15_kernel(
    const float* __restrict__ x, const float* __restrict__ h0, const float* __restrict__ c0,
    const float* __restrict__ W_ih, const float* __restrict__ W_hh,
    const float* __restrict__ b_ih, const float* __restrict__ b_hh,
    const float* __restrict__ W1, const float* __restrict__ b1,
    const float* __restrict__ W2, const float* __restrict__ b2,
    float* __restrict__ out)
{
    const int lane = threadIdx.x;          // block = 64 = one wave = 4 elements
    const int l = lane & 15;               // lane within 16-lane group
    const int e = blockIdx.x * 4 + (lane >> 4);

    const bool owner = (l < HH);
    const int u = owner ? l : 0;
    const float m = owner ? 1.0f : 0.0f;

    // ---- per-lane weights: all 4 gate rows of unit u (f16-packed, pre-scaled) ----
    const int ri = u, rf = 10 + u, rg = 20 + u, ro = 30 + u;
    const float sS = -L2E;          // sigmoid rows: exp2 of -log2e*z
    const float sG = -2.0f * L2E;   // tanh row: exp2 of -2log2e*z
    half2_t Wi[5], Wf[5], Wg[5], Wo[5];
    {
        const float2* pi = (const float2*)(W_hh + ri * HH);
        const float2* pf = (const float2*)(W_hh + rf * HH);
        const float2* pg = (const float2*)(W_hh + rg * HH);
        const float2* po = (const float2*)(W_hh + ro * HH);
#pragma unroll
        for (int p = 0; p < 5; p++) {
            float2 wi = pi[p], wf = pf[p], wg = pg[p], wo = po[p];
            Wi[p] = __builtin_amdgcn_cvt_pkrtz(wi.x * m * sS, wi.y * m * sS);
            Wf[p] = __builtin_amdgcn_cvt_pkrtz(wf.x * m * sS, wf.y * m * sS);
            Wg[p] = __builtin_amdgcn_cvt_pkrtz(wg.x * m * sG, wg.y * m * sG);
            Wo[p] = __builtin_amdgcn_cvt_pkrtz(wo.x * m * sS, wo.y * m * sS);
        }
    }
    const float bi = (b_ih[ri] + b_hh[ri]) * sS;
    const float bf = (b_ih[rf] + b_hh[rf]) * sS;
    const float bg = (b_ih[rg] + b_hh[rg]) * sG;
    const float bo = (b_ih[ro] + b_hh[ro]) * sS;
    const float wii = W_ih[ri] * sS, wif = W_ih[rf] * sS;
    const float wig = W_ih[rg] * sG, wio = W_ih[ro] * sS;

    // ---- regressor row u ----
    half2_t W1p[5];
    {
        const float2* rp = (const float2*)(W1 + u * HH);
#pragma unroll
        for (int p = 0; p < 5; p++) {
            float2 w = rp[p];
            W1p[p] = __builtin_amdgcn_cvt_pkrtz(w.x * m, w.y * m);
        }
    }
    const float b1r = m * b1[u];
    const float W2r = m * W2[u];
    const float seedb = (l == 0) ? b2[0] : 0.0f;   // b2 folded into lane-0 reduce seed

    // ---- state ----
    float c = owner ? c0[e * HH + u] : 0.0f;
    half2_t hp[5];
    {
        float hb[10];
#pragma unroll
        for (int j = 0; j < 10; j++) hb[j] = h0[e * HH + j];
#pragma unroll
        for (int p = 0; p < 5; p++) hp[p] = __builtin_amdgcn_cvt_pkrtz(hb[2 * p], hb[2 * p + 1]);
    }

    const float4* xq  = (const float4*)(x + (size_t)e * TT);
    float4*       ob4 = (float4*)(out + (size_t)e * TT);

    float4 xc = xq[0];
    float4 outv;
    float xprev = 0.0f;   // x of previous step (first regressor result is discarded)

    for (int gb = 0; gb < TT / 4; gb++) {
        const int gbn = (gb + 1) & (TT / 4 - 1);   // wrap: last prefetch reads block 0
        float4 xn = xq[gbn];

#pragma unroll
        for (int r4 = 0; r4 < 4; r4++) {
            const float xv = (r4 == 0) ? xc.x : (r4 == 1) ? xc.y : (r4 == 2) ? xc.z : xc.w;

            // ---- gates(t): 4 lane-local rows, 2-accumulator dot2 trees ----
            float giA = fmaf(xv, wii, bi);
            float gfA = fmaf(xv, wif, bf);
            float ggA = fmaf(xv, wig, bg);
            float goA = fmaf(xv, wio, bo);
            giA = __builtin_amdgcn_fdot2(hp[0], Wi[0], giA, false);
            gfA = __builtin_amdgcn_fdot2(hp[0], Wf[0], gfA, false);
            ggA = __builtin_amdgcn_fdot2(hp[0], Wg[0], ggA, false);
            goA = __builtin_amdgcn_fdot2(hp[0], Wo[0], goA, false);
            giA = __builtin_amdgcn_fdot2(hp[1], Wi[1], giA, false);
            gfA = __builtin_amdgcn_fdot2(hp[1], Wf[1], gfA, false);
            ggA = __builtin_amdgcn_fdot2(hp[1], Wg[1], ggA, false);
            goA = __builtin_amdgcn_fdot2(hp[1], Wo[1], goA, false);
            float giB = __builtin_amdgcn_fdot2(hp[2], Wi[2], 0.0f, false);
            float gfB = __builtin_amdgcn_fdot2(hp[2], Wf[2], 0.0f, false);
            float ggB = __builtin_amdgcn_fdot2(hp[2], Wg[2], 0.0f, false);
            float goB = __builtin_amdgcn_fdot2(hp[2], Wo[2], 0.0f, false);
            giB = __builtin_amdgcn_fdot2(hp[3], Wi[3], giB, false);
            gfB = __builtin_amdgcn_fdot2(hp[3], Wf[3], gfB, false);
            ggB = __builtin_amdgcn_fdot2(hp[3], Wg[3], ggB, false);
            goB = __builtin_amdgcn_fdot2(hp[3], Wo[3], goB, false);
            giB = __builtin_amdgcn_fdot2(hp[4], Wi[4], giB, false);
            gfB = __builtin_amdgcn_fdot2(hp[4], Wf[4], gfB, false);
            ggB = __builtin_amdgcn_fdot2(hp[4], Wg[4], ggB, false);
            goB = __builtin_amdgcn_fdot2(hp[4], Wo[4], goB, false);
            const float gi = giA + giB;
            const float gf = gfA + gfB;
            const float gg = ggA + ggB;
            const float go = goA + goB;

            // ---- regressor(t-1): hp still holds h(t-1); fills the act-chain stall ----
            {
                float aA = b1r, aB;
                aA = __builtin_amdgcn_fdot2(hp[0], W1p[0], aA, false);
                aA = __builtin_amdgcn_fdot2(hp[1], W1p[1], aA, false);
                aB = __builtin_amdgcn_fdot2(hp[2], W1p[2], 0.0f, false);
                aB = __builtin_amdgcn_fdot2(hp[3], W1p[3], aB, false);
                aB = __builtin_amdgcn_fdot2(hp[4], W1p[4], aB, false);
                const float a = aA + aB;
                float part = fmaf(fmaxf(a, 0.0f), W2r, seedb);
                part += dpp_<QP_XOR1>(part);
                part += dpp_<QP_XOR2>(part);
                // parallel rotations off one source + add tree (lane 0 = full sum)
                const float t4  = dpp_<ROR4>(part);
                const float t8  = dpp_<ROR8>(part);
                const float t12 = dpp_<ROR12>(part);
                const float s = (part + t4) + (t8 + t12) + xprev;
                // slot = (step t-1) & 3 = (r4+3)&3
                if (r4 == 0) {
                    outv.w = s;
                    if (gb && l == 0) ob4[gb - 1] = outv;
                }
                else if (r4 == 1) outv.x = s;
                else if (r4 == 2) outv.y = s;
                else outv.z = s;
            }

            // ---- acts + single-rcp cell update ----
            const float A = exp2_(gi);
            const float F = exp2_(gf);
            const float G = exp2_(gg);
            const float O = exp2_(go);
            const float aA1 = 1.0f + A;
            const float aG1 = 1.0f + G;
            const float aF1 = 1.0f + F;
            const float sG1 = 1.0f - G;
            const float P = aA1 * aG1;
            const float D = aF1 * P;
            const float N = fmaf(c, P, aF1 * sG1);
            const float cn = N * rcp_(D);
            c = cn;
            const float T  = exp2_(cn * (-2.0f * L2E));
            const float hq = (1.0f - T) * rcp_((1.0f + O) * (1.0f + T));

            // ---- pure-DPP packed h broadcast (trimmed: banks 0-2 only) ----
            const float hq_p = dpp_<QP_XOR1>(hq);
            // even lanes (the only broadcast sources) get (h_2j, h_2j+1)
            half2_t pkh = __builtin_amdgcn_cvt_pkrtz(hq, hq_p);
            const int pk = *(const int*)&pkh;
            const int A_ = dppi_<QP_B0>(0, pk);   // quad q sees pk_{2q}
            const int B_ = dppi_<QP_B2>(0, pk);   // quad q sees pk_{2q+1}
            int h0i = A_;                          // pk0 @ quad0
            h0i = dppi_<ROR12, 0x2>(h0i, A_);
            h0i = dppi_<ROR8,  0x4>(h0i, A_);
            int h1i = B_;                          // pk1 @ quad0
            h1i = dppi_<ROR12, 0x2>(h1i, B_);
            h1i = dppi_<ROR8,  0x4>(h1i, B_);
            int h2i = A_;                          // pk2 @ quad1
            h2i = dppi_<ROR4,  0x1>(h2i, A_);
            h2i = dppi_<ROR12, 0x4>(h2i, A_);
            int h3i = B_;                          // pk3 @ quad1
            h3i = dppi_<ROR4,  0x1>(h3i, B_);
            h3i = dppi_<ROR12, 0x4>(h3i, B_);
            int h4i = A_;                          // pk4 @ quad2
            h4i = dppi_<ROR8,  0x1>(h4i, A_);
            h4i = dppi_<ROR4,  0x2>(h4i, A_);
            hp[0] = *(const half2_t*)&h0i;
            hp[1] = *(const half2_t*)&h1i;
            hp[2] = *(const half2_t*)&h2i;
            hp[3] = *(const half2_t*)&h3i;
            hp[4] = *(const half2_t*)&h4i;

            xprev = xv;
        }

        xc = xn;
    }

    // ---- epilogue: regressor for step TT-1 (hp = h(TT-1), xprev = x(TT-1)) ----
    {
        float aA = b1r, aB;
        aA = __builtin_amdgcn_fdot2(hp[0], W1p[0], aA, false);
        aA = __builtin_amdgcn_fdot2(hp[1], W1p[1], aA, false);
        aB = __builtin_amdgcn_fdot2(hp[2], W1p[2], 0.0f, false);
        aB = __builtin_amdgcn_fdot2(hp[3], W1p[3], aB, false);
        aB = __builtin_amdgcn_fdot2(hp[4], W1p[4], aB, false);
        const float a = aA + aB;
        float part = fmaf(fmaxf(a, 0.0f), W2r, seedb);
        part += dpp_<QP_XOR1>(part);
        part += dpp_<QP_XOR2>(part);
        const float t4  = dpp_<ROR4>(part);
        const float t8  = dpp_<ROR8>(part);
        const float t12 = dpp_<ROR12>(part);
        outv.w = (part + t4) + (t8 + t12) + xprev;
        if (l == 0) ob4[TT / 4 - 1] = outv;
    }
}

extern "C" void kernel_launch(void* const* d_in, const int* in_sizes, int n_in,
                              void* d_out, int out_size, void* d_ws, size_t ws_size,
                              hipStream_t stream) {
    const float* x    = (const float*)d_in[0];
    const float* h0   = (const float*)d_in[1];
    const float* c0   = (const float*)d_in[2];
    const float* W_ih = (const float*)d_in[3];
    const float* W_hh = (const float*)d_in[4];
    const float* b_ih = (const float*)d_in[5];
    const float* b_hh = (const float*)d_in[6];
    const float* W1   = (const float*)d_in[7];
    const float* b1   = (const float*)d_in[8];
    const float* W2   = (const float*)d_in[9];
    const float* b2   = (const float*)d_in[10];
    float* out = (float*)d_out;

    dim3 grid(BB * 16 / 64);   // 1024 blocks: 4 waves/CU (1 per SIMD)
    dim3 block(64);
    lstm16r15_kernel<<<grid, block, 0, stream>>>(x, h0, c0, W_ih, W_hh, b_ih, b_hh,
                                                 W1, b1, W2, b2, out);
}

// Round 16
// 97.380 us; speedup vs baseline: 1.0758x; 1.0758x over previous
//
#include <hip/hip_runtime.h>

#define BB 4096
#define TT 512
#define HH 10
#define L2E 1.44269504088896340736f

typedef __fp16 half2_t __attribute__((ext_vector_type(2)));

__device__ __forceinline__ float rcp_(float x) { return __builtin_amdgcn_rcpf(x); }
__device__ __forceinline__ float exp2_(float x) { return __builtin_amdgcn_exp2f(x); }

// DPP helpers. quad_perm ctrl 0x00-0xFF; row_ror:N = 0x120|N (dst[i] = src[(i+N)&15],
// within each 16-lane row). update_dpp(old, src, ctrl, row_mask, bank_mask, bound):
// lanes outside row/bank masks keep `old` — used to merge rotations into one register.
template <int CTRL, int BANK = 0xF>
__device__ __forceinline__ int dppi_(int old, int src) {
    return __builtin_amdgcn_update_dpp(old, src, CTRL, 0xF, BANK, true);
}
template <int CTRL>
__device__ __forceinline__ float dpp_(float v) {
    return __int_as_float(__builtin_amdgcn_update_dpp(
        0, __float_as_int(v), CTRL, 0xF, 0xF, true));
}
#define QP_XOR1 0xB1   // [1,0,3,2]
#define QP_XOR2 0x4E   // [2,3,0,1]
#define QP_B0   0x00   // broadcast quad lane 0
#define QP_B2   0xAA   // broadcast quad lane 2
#define ROR4    0x124
#define ROR8    0x128
#define ROR12   0x12C

// 16 lanes per batch element (4 elements/wave, 1024 waves = 1/SIMD chip-wide).
// Owner lane u<10 holds all 4 gate rows {u,10+u,20+u,30+u}, f16-packed for
// v_dot2_f32_f16, PRE-SCALED by -log2e / -2log2e so accumulators feed exp2 directly.
// Merged-rcp activations: sigma(i)tanh(g) = (1-G)/((1+A)(1+G)); h = (1-T)/((1+O)(1+T)).
// SOFTWARE-PIPELINED REGRESSOR: at iteration t, hp still holds h(t-1), so the
// step-(t-1) regressor executes between step-t's gate dot2s and its serial
// act->c->h->broadcast chain, filling the chain's stall slots. Output slots shift by
// one sub-step (slot (r4+3)&3); float4 stored at r4==0 of the NEXT gb; epilogue does
// step 511. Broadcast tree trimmed: bank-3 (lanes 12-15, zero-weight) merges dropped,
// pair-pack sels dropped (only even quad-lanes are broadcast sources).
// [r15 post-mortem: 2-acc dot2 trees + single-rcp + parallel reduce tail REGRESSED
//  (97.5 -> 104.8 us, busy up, wall up) — this is the exact r14 revert.]
__global__ __launch_bounds__(64) void lstm16pipe_kernel(
    const float* __restrict__ x, const float* __restrict__ h0, const float* __restrict__ c0,
    const float* __restrict__ W_ih, const float* __restrict__ W_hh,
    const float* __restrict__ b_ih, const float* __restrict__ b_hh,
    const float* __restrict__ W1, const float* __restrict__ b1,
    const float* __restrict__ W2, const float* __restrict__ b2,
    float* __restrict__ out)
{
    const int lane = threadIdx.x;          // block = 64 = one wave = 4 elements
    const int l = lane & 15;               // lane within 16-lane group
    const int e = blockIdx.x * 4 + (lane >> 4);

    const bool owner = (l < HH);
    const int u = owner ? l : 0;
    const float m = owner ? 1.0f : 0.0f;

    // ---- per-lane weights: all 4 gate rows of unit u (f16-packed, pre-scaled) ----
    const int ri = u, rf = 10 + u, rg = 20 + u, ro = 30 + u;
    const float sS = -L2E;          // sigmoid rows: exp2 of -log2e*z
    const float sG = -2.0f * L2E;   // tanh row: exp2 of -2log2e*z
    half2_t Wi[5], Wf[5], Wg[5], Wo[5];
    {
        const float2* pi = (const float2*)(W_hh + ri * HH);
        const float2* pf = (const float2*)(W_hh + rf * HH);
        const float2* pg = (const float2*)(W_hh + rg * HH);
        const float2* po = (const float2*)(W_hh + ro * HH);
#pragma unroll
        for (int p = 0; p < 5; p++) {
            float2 wi = pi[p], wf = pf[p], wg = pg[p], wo = po[p];
            Wi[p] = __builtin_amdgcn_cvt_pkrtz(wi.x * m * sS, wi.y * m * sS);
            Wf[p] = __builtin_amdgcn_cvt_pkrtz(wf.x * m * sS, wf.y * m * sS);
            Wg[p] = __builtin_amdgcn_cvt_pkrtz(wg.x * m * sG, wg.y * m * sG);
            Wo[p] = __builtin_amdgcn_cvt_pkrtz(wo.x * m * sS, wo.y * m * sS);
        }
    }
    const float bi = (b_ih[ri] + b_hh[ri]) * sS;
    const float bf = (b_ih[rf] + b_hh[rf]) * sS;
    const float bg = (b_ih[rg] + b_hh[rg]) * sG;
    const float bo = (b_ih[ro] + b_hh[ro]) * sS;
    const float wii = W_ih[ri] * sS, wif = W_ih[rf] * sS;
    const float wig = W_ih[rg] * sG, wio = W_ih[ro] * sS;

    // ---- regressor row u ----
    half2_t W1p[5];
    {
        const float2* rp = (const float2*)(W1 + u * HH);
#pragma unroll
        for (int p = 0; p < 5; p++) {
            float2 w = rp[p];
            W1p[p] = __builtin_amdgcn_cvt_pkrtz(w.x * m, w.y * m);
        }
    }
    const float b1r = m * b1[u];
    const float W2r = m * W2[u];
    const float seedb = (l == 0) ? b2[0] : 0.0f;   // b2 folded into lane-0 reduce seed

    // ---- state ----
    float c = owner ? c0[e * HH + u] : 0.0f;
    half2_t hp[5];
    {
        float hb[10];
#pragma unroll
        for (int j = 0; j < 10; j++) hb[j] = h0[e * HH + j];
#pragma unroll
        for (int p = 0; p < 5; p++) hp[p] = __builtin_amdgcn_cvt_pkrtz(hb[2 * p], hb[2 * p + 1]);
    }

    const float4* xq  = (const float4*)(x + (size_t)e * TT);
    float4*       ob4 = (float4*)(out + (size_t)e * TT);

    float4 xc = xq[0];
    float4 outv;
    float xprev = 0.0f;   // x of previous step (first regressor result is discarded)

    for (int gb = 0; gb < TT / 4; gb++) {
        const int gbn = (gb + 1) & (TT / 4 - 1);   // wrap: last prefetch reads block 0
        float4 xn = xq[gbn];

#pragma unroll
        for (int r4 = 0; r4 < 4; r4++) {
            const float xv = (r4 == 0) ? xc.x : (r4 == 1) ? xc.y : (r4 == 2) ? xc.z : xc.w;

            // ---- gates(t): 4 lane-local rows, pre-scaled accumulators ----
            float gi = fmaf(xv, wii, bi);
            float gf = fmaf(xv, wif, bf);
            float gg = fmaf(xv, wig, bg);
            float go = fmaf(xv, wio, bo);
#pragma unroll
            for (int p = 0; p < 5; p++) {
                gi = __builtin_amdgcn_fdot2(hp[p], Wi[p], gi, false);
                gf = __builtin_amdgcn_fdot2(hp[p], Wf[p], gf, false);
                gg = __builtin_amdgcn_fdot2(hp[p], Wg[p], gg, false);
                go = __builtin_amdgcn_fdot2(hp[p], Wo[p], go, false);
            }

            // ---- regressor(t-1): hp still holds h(t-1); fills the act-chain stall ----
            {
                float a = b1r;
#pragma unroll
                for (int p = 0; p < 5; p++)
                    a = __builtin_amdgcn_fdot2(hp[p], W1p[p], a, false);
                float part = fmaf(fmaxf(a, 0.0f), W2r, seedb);
                part += dpp_<QP_XOR1>(part);
                part += dpp_<QP_XOR2>(part);
                part += dpp_<ROR4>(part);
                part += dpp_<ROR8>(part);
                const float s = part + xprev;
                // slot = (step t-1) & 3 = (r4+3)&3
                if (r4 == 0) {
                    outv.w = s;
                    if (gb && l == 0) ob4[gb - 1] = outv;
                }
                else if (r4 == 1) outv.x = s;
                else if (r4 == 2) outv.y = s;
                else outv.z = s;
            }

            // ---- acts + c/h update ----
            const float A = exp2_(gi);
            const float F = exp2_(gf);
            const float G = exp2_(gg);
            const float O = exp2_(go);
            const float af = rcp_(1.0f + F);
            const float q  = (1.0f - G) * rcp_((1.0f + A) * (1.0f + G));
            const float cn = fmaf(af, c, q);
            c = cn;
            const float T  = exp2_(cn * (-2.0f * L2E));
            const float hq = (1.0f - T) * rcp_((1.0f + O) * (1.0f + T));

            // ---- pure-DPP packed h broadcast (trimmed: banks 0-2 only) ----
            const float hq_p = dpp_<QP_XOR1>(hq);
            // even lanes (the only broadcast sources) get (h_2j, h_2j+1)
            half2_t pkh = __builtin_amdgcn_cvt_pkrtz(hq, hq_p);
            const int pk = *(const int*)&pkh;
            const int A_ = dppi_<QP_B0>(0, pk);   // quad q sees pk_{2q}
            const int B_ = dppi_<QP_B2>(0, pk);   // quad q sees pk_{2q+1}
            int h0i = A_;                          // pk0 @ quad0
            h0i = dppi_<ROR12, 0x2>(h0i, A_);
            h0i = dppi_<ROR8,  0x4>(h0i, A_);
            int h1i = B_;                          // pk1 @ quad0
            h1i = dppi_<ROR12, 0x2>(h1i, B_);
            h1i = dppi_<ROR8,  0x4>(h1i, B_);
            int h2i = A_;                          // pk2 @ quad1
            h2i = dppi_<ROR4,  0x1>(h2i, A_);
            h2i = dppi_<ROR12, 0x4>(h2i, A_);
            int h3i = B_;                          // pk3 @ quad1
            h3i = dppi_<ROR4,  0x1>(h3i, B_);
            h3i = dppi_<ROR12, 0x4>(h3i, B_);
            int h4i = A_;                          // pk4 @ quad2
            h4i = dppi_<ROR8,  0x1>(h4i, A_);
            h4i = dppi_<ROR4,  0x2>(h4i, A_);
            hp[0] = *(const half2_t*)&h0i;
            hp[1] = *(const half2_t*)&h1i;
            hp[2] = *(const half2_t*)&h2i;
            hp[3] = *(const half2_t*)&h3i;
            hp[4] = *(const half2_t*)&h4i;

            xprev = xv;
        }

        xc = xn;
    }

    // ---- epilogue: regressor for step TT-1 (hp = h(TT-1), xprev = x(TT-1)) ----
    {
        float a = b1r;
#pragma unroll
        for (int p = 0; p < 5; p++)
            a = __builtin_amdgcn_fdot2(hp[p], W1p[p], a, false);
        float part = fmaf(fmaxf(a, 0.0f), W2r, seedb);
        part += dpp_<QP_XOR1>(part);
        part += dpp_<QP_XOR2>(part);
        part += dpp_<ROR4>(part);
        part += dpp_<ROR8>(part);
        outv.w = part + xprev;
        if (l == 0) ob4[TT / 4 - 1] = outv;
    }
}

extern "C" void kernel_launch(void* const* d_in, const int* in_sizes, int n_in,
                              void* d_out, int out_size, void* d_ws, size_t ws_size,
                              hipStream_t stream) {
    const float* x    = (const float*)d_in[0];
    const float* h0   = (const float*)d_in[1];
    const float* c0   = (const float*)d_in[2];
    const float* W_ih = (const float*)d_in[3];
    const float* W_hh = (const float*)d_in[4];
    const float* b_ih = (const float*)d_in[5];
    const float* b_hh = (const float*)d_in[6];
    const float* W1   = (const float*)d_in[7];
    const float* b1   = (const float*)d_in[8];
    const float* W2   = (const float*)d_in[9];
    const float* b2   = (const float*)d_in[10];
    float* out = (float*)d_out;

    dim3 grid(BB * 16 / 64);   // 1024 blocks: 4 waves/CU (1 per SIMD)
    dim3 block(64);
    lstm16pipe_kernel<<<grid, block, 0, stream>>>(x, h0, c0, W_ih, W_hh, b_ih, b_hh,
                                                  W1, b1, W2, b2, out);
}